// Round 8
// baseline (437.735 us; speedup 1.0000x reference)
//
#include <hip/hip_runtime.h>

#define NN 100000
#define SE 16
#define NE 1600000        // NN*SE
#define BB 4096
#define CAP 64            // per-node bucket capacity (deg ~ Poisson(16))
#define NBIN 250          // fine bins of 400 nodes: 250*400 = 100000 exactly
#define BINW 400
#define SEGCAP 12288      // per-bin segment capacity (avg 6400 + align waste ~3000)
#define NP1 391           // ceil(NE / 4096)

__device__ __forceinline__ float leaky(float x) { return x > 0.0f ? x : 0.2f * x; }

__device__ __forceinline__ unsigned short f2bf(float f) {     // RNE f32 -> bf16
    unsigned u = __float_as_uint(f);
    u += 0x7fffu + ((u >> 16) & 1u);
    return (unsigned short)(u >> 16);
}
__device__ __forceinline__ float bf2f(unsigned short h) {
    return __uint_as_float(((unsigned)h) << 16);
}
__device__ __forceinline__ float4 ldh(const ushort4* __restrict__ hb, size_t idx) {
    ushort4 v = hb[idx];
    float4 r;
    r.x = bf2f(v.x); r.y = bf2f(v.y); r.z = bf2f(v.z); r.w = bf2f(v.w);
    return r;
}

#define FMA4(a, sx, wv) \
    a.x = fmaf(sx, wv.x, a.x); a.y = fmaf(sx, wv.y, a.y); \
    a.z = fmaf(sx, wv.z, a.z); a.w = fmaf(sx, wv.w, a.w);

// ---------------- pass 1: bin edges by dst into 250 segments ----------------
__global__ __launch_bounds__(256) void k_bin(const int* __restrict__ edges,
                                             int* __restrict__ cursor,
                                             unsigned* __restrict__ pairs) {
    __shared__ int hist[NBIN];
    __shared__ int gbase[NBIN];
    __shared__ int resv[NBIN];
    __shared__ int off[NBIN];
    const int tid = threadIdx.x;
    const int e0  = blockIdx.x * 4096;

    if (tid < NBIN) hist[tid] = 0;
    __syncthreads();

    int pb[16];   // packed pair
    int bn[16];   // bin (-1 = invalid)
#pragma unroll
    for (int it = 0; it < 16; ++it) {
        int e = e0 + it * 256 + tid;
        int b = -1, pr = 0;
        if (e < NE) {
            int j = __builtin_nontemporal_load(&edges[e]);
            int i = e >> 4;
            if (j != i) {
                b  = j / BINW;
                pr = ((j - b * BINW) << 17) | i;
            }
        }
        bn[it] = b; pb[it] = pr;
        if (b >= 0) atomicAdd(&hist[b], 1);
    }
    __syncthreads();

    if (tid < NBIN) {
        int c   = hist[tid];
        int res = (c + 15) & ~15;          // line-aligned reservation
        int gb  = res ? atomicAdd(&cursor[tid], res) : 0;
        if (gb + res > SEGCAP) gb = SEGCAP;   // overflow guard (statistically never)
        gbase[tid] = gb; resv[tid] = res; off[tid] = 0;
    }
    __syncthreads();

#pragma unroll
    for (int it = 0; it < 16; ++it) {
        int b = bn[it];
        if (b >= 0) {
            int o   = atomicAdd(&off[b], 1);
            int pos = gbase[b] + o;
            if (pos < SEGCAP) pairs[(size_t)b * SEGCAP + pos] = (unsigned)pb[it];
        }
    }
    __syncthreads();

    if (tid < NBIN) {                      // sentinel-fill alignment gap
        int base = gbase[tid];
        for (int k = hist[tid]; k < resv[tid]; ++k) {
            int pos = base + k;
            if (pos < SEGCAP) pairs[(size_t)tid * SEGCAP + pos] = 0xFFFFFFFFu;
        }
    }
}

// ---------------- pass 2: segment -> per-node buckets ----------------
__global__ __launch_bounds__(256) void k_scat(const unsigned* __restrict__ pairs,
                                              const int* __restrict__ cursor,
                                              int* __restrict__ cnt,
                                              int* __restrict__ esrc) {
    __shared__ int lcnt[112];
    const int bin = blockIdx.x >> 2;
    const int sub = blockIdx.x & 3;
    const int jl0 = sub * 112;
    const int jl1 = (jl0 + 112 < BINW) ? jl0 + 112 : BINW;   // sub3: 336..400
    const int nloc = jl1 - jl0;
    if (threadIdx.x < nloc) lcnt[threadIdx.x] = 0;
    __syncthreads();

    int n = cursor[bin]; if (n > SEGCAP) n = SEGCAP;
    const unsigned* seg = pairs + (size_t)bin * SEGCAP;
    for (int k = threadIdx.x; k < n; k += 256) {
        unsigned pr = seg[k];
        if ((int)pr < 0) continue;         // sentinel
        int jl = (int)(pr >> 17);
        if (jl < jl0 || jl >= jl1) continue;
        int i = (int)(pr & 0x1FFFFu);
        int p = atomicAdd(&lcnt[jl - jl0], 1);
        if (p < CAP) esrc[((size_t)(bin * BINW + jl)) * CAP + p] = i;
    }
    __syncthreads();
    if (threadIdx.x < nloc) cnt[bin * BINW + jl0 + threadIdx.x] = lcnt[threadIdx.x];
}

// ---------------- h = X@W (bf16 out) + s,t ----------------
// 32-row tile per block (3125 blocks exact). 2 rows/thread -> live set
// {2 acc, 4 W, 2 x} ~ 60 VGPR; __launch_bounds__(256,4) caps at 128.
// xr padded to 17 float4 -> the 4 sub-groups of a wave hit banks
// {0-3},{8-11},{16-19},{24-27}: conflict-free. Wl reads are 2-way (free).
__global__ __launch_bounds__(256, 4) void k_mm(const float4* __restrict__ X4,
                                               const float4* __restrict__ W4,
                                               const float* __restrict__ att,
                                               ushort4* __restrict__ hb,
                                               float* __restrict__ s,
                                               float* __restrict__ t) {
    __shared__ float4 Wl[64][16];    // Wl[k][q] = W[k][4q..4q+3]
    __shared__ float4 xr[32][17];    // 32 staged rows, padded
    const int tid  = threadIdx.x;
    const int lane = tid & 63;
    const int q    = lane & 15;
    const int slot = ((tid >> 6) << 2) | (lane >> 4);   // 0..15
    const int r0   = blockIdx.x * 32;

    for (int idx = tid; idx < 1024; idx += 256)
        Wl[idx >> 4][idx & 15] = W4[idx];
#pragma unroll
    for (int u = 0; u < 2; ++u) {
        int idx = u * 256 + tid;
        xr[idx >> 4][idx & 15] = X4[(size_t)(r0 + (idx >> 4)) * 16 + (idx & 15)];
    }
    __syncthreads();

    const int rbase = slot * 2;
    float4 acc0 = {0,0,0,0}, acc1 = {0,0,0,0};
#pragma unroll
    for (int k4 = 0; k4 < 16; ++k4) {
        float4 w0 = Wl[k4 * 4 + 0][q];
        float4 w1 = Wl[k4 * 4 + 1][q];
        float4 w2 = Wl[k4 * 4 + 2][q];
        float4 w3 = Wl[k4 * 4 + 3][q];
        float4 x0 = xr[rbase + 0][k4];
        float4 x1 = xr[rbase + 1][k4];
        FMA4(acc0, x0.x, w0) FMA4(acc0, x0.y, w1) FMA4(acc0, x0.z, w2) FMA4(acc0, x0.w, w3)
        FMA4(acc1, x1.x, w0) FMA4(acc1, x1.y, w1) FMA4(acc1, x1.z, w2) FMA4(acc1, x1.w, w3)
    }

    const float4 ai = ((const float4*)att)[q];
    const float4 aj = ((const float4*)att)[16 + q];
#pragma unroll
    for (int rr = 0; rr < 2; ++rr) {
        float4 a = rr ? acc1 : acc0;
        int row = r0 + rbase + rr;
        ushort4 hv;
        hv.x = f2bf(a.x); hv.y = f2bf(a.y); hv.z = f2bf(a.z); hv.w = f2bf(a.w);
        hb[(size_t)row * 16 + q] = hv;
        float ps = a.x * ai.x + a.y * ai.y + a.z * ai.z + a.w * ai.w;
        float pt = a.x * aj.x + a.y * aj.y + a.z * aj.z + a.w * aj.w;
#pragma unroll
        for (int off = 1; off < 16; off <<= 1) {
            ps += __shfl_xor(ps, off);
            pt += __shfl_xor(pt, off);
        }
        if (q == 0) { s[row] = ps; t[row] = pt; }
    }
}

// ---------------- gather-softmax-aggregate ----------------
// 4 nodes/wave, 16 lanes x 4 dims (bf16 gathers, 128 B/edge).
// No max subtraction: |alpha| <= ~3, exp is exact-safe in f32.
__global__ __launch_bounds__(256) void k_gat(const ushort4* __restrict__ hb,
                                             const int* __restrict__ cnt,
                                             const int* __restrict__ esrc,
                                             const float* __restrict__ s,
                                             const float* __restrict__ t,
                                             const float* __restrict__ bias,
                                             float4* __restrict__ g4) {
    const int tid  = threadIdx.x;
    const int lane = tid & 63;
    const int w    = tid >> 6;
    const int q    = lane & 15;
    const int sub  = lane >> 4;
    const int j    = blockIdx.x * 16 + w * 4 + sub;   // 6250*16 = 100000 exact
    const int lsrc = sub * 16;

    const float sj = s[j];
    int deg = __builtin_nontemporal_load(&cnt[j]); if (deg > CAP) deg = CAP;
    const int base = j * CAP;

    // parallel edge phase: lane q handles edges q, q+16, q+32, q+48 of its node
    int   sc[4] = {0, 0, 0, 0};
    float ev[4] = {0.f, 0.f, 0.f, 0.f};
#pragma unroll
    for (int u = 0; u < 4; ++u) {
        int e = q + u * 16;
        if (e < deg) {
            int srcn = __builtin_nontemporal_load(&esrc[base + e]);
            sc[u] = srcn;
            ev[u] = expf(leaky(sj + t[srcn]));
        }
    }
    float den = ev[0] + ev[1] + ev[2] + ev[3];
#pragma unroll
    for (int off = 1; off < 16; off <<= 1) den += __shfl_xor(den, off);

    // self loop
    float evs = expf(leaky(sj + t[j]));
    den += evs;
    float4 hj = ldh(hb, (size_t)j * 16 + q);
    float4 acc;
    acc.x = evs * hj.x; acc.y = evs * hj.y; acc.z = evs * hj.z; acc.w = evs * hj.w;

    // serial accumulate: 4 independent chains per wave, loads batched 4-deep
#pragma unroll
    for (int u = 0; u < 4; ++u) {
        if (!__any(deg > u * 16)) break;
#pragma unroll
        for (int kk = 0; kk < 16; kk += 4) {
            int e0 = u * 16 + kk;
            if (!__any(deg > e0)) break;
            int   sA = __shfl(sc[u], lsrc + kk + 0);
            int   sB = __shfl(sc[u], lsrc + kk + 1);
            int   sC = __shfl(sc[u], lsrc + kk + 2);
            int   sD = __shfl(sc[u], lsrc + kk + 3);
            float eA = __shfl(ev[u], lsrc + kk + 0);
            float eB = __shfl(ev[u], lsrc + kk + 1);
            float eC = __shfl(ev[u], lsrc + kk + 2);
            float eD = __shfl(ev[u], lsrc + kk + 3);
            float4 vA = {0,0,0,0}, vB = {0,0,0,0}, vC = {0,0,0,0}, vD = {0,0,0,0};
            if (e0 + 0 < deg) vA = ldh(hb, (size_t)sA * 16 + q);
            if (e0 + 1 < deg) vB = ldh(hb, (size_t)sB * 16 + q);
            if (e0 + 2 < deg) vC = ldh(hb, (size_t)sC * 16 + q);
            if (e0 + 3 < deg) vD = ldh(hb, (size_t)sD * 16 + q);
            FMA4(acc, eA, vA) FMA4(acc, eB, vB) FMA4(acc, eC, vC) FMA4(acc, eD, vD)
        }
    }

    float4 bv = ((const float4*)bias)[q];
    float inv = 1.0f / (den + 1e-16f);
    float4 v;
    v.x = acc.x * inv + bv.x; v.y = acc.y * inv + bv.y;
    v.z = acc.z * inv + bv.z; v.w = acc.w * inv + bv.w;
    float sq = v.x * v.x + v.y * v.y + v.z * v.z + v.w * v.w;
#pragma unroll
    for (int off = 1; off < 16; off <<= 1) sq += __shfl_xor(sq, off);
    float nm = fmaxf(sqrtf(sq), 1e-12f);
    float4 o;
    o.x = v.x / nm; o.y = v.y / nm; o.z = v.z / nm; o.w = v.w / nm;
    g4[(size_t)j * 16 + q] = o;
}

// ---------------- scores + reg loss ----------------
__global__ __launch_bounds__(256) void k5_score(const float4* __restrict__ X4,
                                                const float4* __restrict__ g4,
                                                const int* __restrict__ user,
                                                const int* __restrict__ pos,
                                                const int* __restrict__ neg,
                                                const int* __restrict__ posr,
                                                const int* __restrict__ negr,
                                                float* __restrict__ out) {
    const int tid  = threadIdx.x;
    const int lane = tid & 63;
    const int q    = lane & 15;
    const int sub  = lane >> 4;
    const int b    = blockIdx.x * 16 + (tid >> 6) * 4 + sub;

    int u = user[b], p = pos[b], n = neg[b], pr = posr[b], nr = negr[b];
    float4 xu = X4[(size_t)u * 16 + q],  gu = g4[(size_t)u * 16 + q];
    float4 xp = X4[(size_t)p * 16 + q],  gp = g4[(size_t)p * 16 + q];
    float4 xn = X4[(size_t)n * 16 + q],  gn = g4[(size_t)n * 16 + q];
    float4 xq = X4[(size_t)pr * 16 + q], gq = g4[(size_t)pr * 16 + q];
    float4 xm = X4[(size_t)nr * 16 + q], gm = g4[(size_t)nr * 16 + q];

#define DOT(a, c) (a.x * c.x + a.y * c.y + a.z * c.z + a.w * c.w)
    float dp = DOT(xu, xp) + DOT(gu, gp);
    float dn = DOT(xu, xn) + DOT(gu, gn);
    float dq = DOT(xu, xq) + DOT(gu, gq);
    float dm = DOT(xu, xm) + DOT(gu, gm);
    float rg = 0.5f    * (DOT(xu, xu) + DOT(gu, gu) + DOT(xp, xp) + DOT(gp, gp)
                        + DOT(xn, xn) + DOT(gn, gn))
             + 0.0005f * (DOT(xq, xq) + DOT(gq, gq) + DOT(xm, xm) + DOT(gm, gm));
#undef DOT
#pragma unroll
    for (int off = 1; off < 16; off <<= 1) {
        dp += __shfl_xor(dp, off);
        dn += __shfl_xor(dn, off);
        dq += __shfl_xor(dq, off);
        dm += __shfl_xor(dm, off);
    }
    if (q == 0) {
        out[b]      = dp + 0.1f * dq;
        out[BB + b] = dn + 0.1f * dm;
    }
#pragma unroll
    for (int off = 16; off < 64; off <<= 1) rg += __shfl_xor(rg, off);
#pragma unroll
    for (int off = 1; off < 16; off <<= 1) rg += __shfl_xor(rg, off);
    if (lane == 0) unsafeAtomicAdd(&out[2 * BB], rg);
}

extern "C" void kernel_launch(void* const* d_in, const int* in_sizes, int n_in,
                              void* d_out, int out_size, void* d_ws, size_t ws_size,
                              hipStream_t stream) {
    const float* X    = (const float*)d_in[0];
    const float* W    = (const float*)d_in[1];
    const float* att  = (const float*)d_in[2];
    const float* bias = (const float*)d_in[3];
    const int* edges  = (const int*)d_in[4];
    const int* user   = (const int*)d_in[5];
    const int* pos    = (const int*)d_in[6];
    const int* neg    = (const int*)d_in[7];
    const int* posr   = (const int*)d_in[8];
    const int* negr   = (const int*)d_in[9];
    float* out = (float*)d_out;

    ushort4*  hb     = (ushort4*)d_ws;                       // NN*16 ushort4 (bf16 h)
    float4*   g4     = (float4*)(hb + (size_t)NN * 16);      // NN*16 float4
    float*    s      = (float*)(g4 + (size_t)NN * 16);       // NN
    float*    t      = s + NN;                               // NN
    int*      cnt    = (int*)(t + NN);                       // NN
    int*      esrc   = cnt + NN;                             // NN*CAP
    unsigned* pairs  = (unsigned*)(esrc + (size_t)NN * CAP); // NBIN*SEGCAP
    int*      cursor = (int*)(pairs + (size_t)NBIN * SEGCAP);// NBIN

    hipMemsetAsync(cursor, 0, 256 * sizeof(int), stream);
    hipMemsetAsync(out, 0, (size_t)(2 * BB + 1) * sizeof(float), stream);

    k_bin<<<NP1, 256, 0, stream>>>(edges, cursor, pairs);
    k_scat<<<NBIN * 4, 256, 0, stream>>>(pairs, cursor, cnt, esrc);
    k_mm<<<3125, 256, 0, stream>>>((const float4*)X, (const float4*)W, att, hb, s, t);
    k_gat<<<6250, 256, 0, stream>>>(hb, cnt, esrc, s, t, bias, g4);
    k5_score<<<256, 256, 0, stream>>>((const float4*)X, g4, user, pos, neg, posr, negr, out);
}

// Round 9
// 149.707 us; speedup vs baseline: 2.9239x; 2.9239x over previous
//
#include <hip/hip_runtime.h>

#define NN 100000
#define SE 16
#define NE 1600000        // NN*SE
#define BB 4096
#define CAP 64            // per-node bucket capacity (deg ~ Poisson(16))
#define NBIN 250          // fine bins of 400 nodes: 250*400 = 100000 exactly
#define BINW 400
#define SEGCAP 12288      // per-bin segment capacity (avg 6400 + align waste ~3000)
#define NP1 391           // ceil(NE / 4096)
#define NMMB 1563         // ceil(NN/64) one 64-row tile per block

__device__ __forceinline__ float leaky(float x) { return x > 0.0f ? x : 0.2f * x; }

__device__ __forceinline__ unsigned short f2bf(float f) {     // RNE f32 -> bf16
    unsigned u = __float_as_uint(f);
    u += 0x7fffu + ((u >> 16) & 1u);
    return (unsigned short)(u >> 16);
}
__device__ __forceinline__ float bf2f(unsigned short h) {
    return __uint_as_float(((unsigned)h) << 16);
}
__device__ __forceinline__ float4 ldh(const ushort4* __restrict__ hb, size_t idx) {
    ushort4 v = hb[idx];
    float4 r;
    r.x = bf2f(v.x); r.y = bf2f(v.y); r.z = bf2f(v.z); r.w = bf2f(v.w);
    return r;
}

#define FMA4(a, sx, wv) \
    a.x = fmaf(sx, wv.x, a.x); a.y = fmaf(sx, wv.y, a.y); \
    a.z = fmaf(sx, wv.z, a.z); a.w = fmaf(sx, wv.w, a.w);

// ---------------- pass 1: bin edges by dst into 250 segments ----------------
__global__ __launch_bounds__(256) void k_bin(const int* __restrict__ edges,
                                             int* __restrict__ cursor,
                                             unsigned* __restrict__ pairs) {
    __shared__ int hist[NBIN];
    __shared__ int gbase[NBIN];
    __shared__ int resv[NBIN];
    __shared__ int off[NBIN];
    const int tid = threadIdx.x;
    const int e0  = blockIdx.x * 4096;

    if (tid < NBIN) hist[tid] = 0;
    __syncthreads();

    int pb[16];   // packed pair
    int bn[16];   // bin (-1 = invalid)
#pragma unroll
    for (int it = 0; it < 16; ++it) {
        int e = e0 + it * 256 + tid;
        int b = -1, pr = 0;
        if (e < NE) {
            int j = __builtin_nontemporal_load(&edges[e]);
            int i = e >> 4;
            if (j != i) {
                b  = j / BINW;
                pr = ((j - b * BINW) << 17) | i;
            }
        }
        bn[it] = b; pb[it] = pr;
        if (b >= 0) atomicAdd(&hist[b], 1);
    }
    __syncthreads();

    if (tid < NBIN) {
        int c   = hist[tid];
        int res = (c + 15) & ~15;          // line-aligned reservation
        int gb  = res ? atomicAdd(&cursor[tid], res) : 0;
        if (gb + res > SEGCAP) gb = SEGCAP;   // overflow guard (statistically never)
        gbase[tid] = gb; resv[tid] = res; off[tid] = 0;
    }
    __syncthreads();

#pragma unroll
    for (int it = 0; it < 16; ++it) {
        int b = bn[it];
        if (b >= 0) {
            int o   = atomicAdd(&off[b], 1);
            int pos = gbase[b] + o;
            if (pos < SEGCAP) pairs[(size_t)b * SEGCAP + pos] = (unsigned)pb[it];
        }
    }
    __syncthreads();

    if (tid < NBIN) {                      // sentinel-fill alignment gap
        int base = gbase[tid];
        for (int k = hist[tid]; k < resv[tid]; ++k) {
            int pos = base + k;
            if (pos < SEGCAP) pairs[(size_t)tid * SEGCAP + pos] = 0xFFFFFFFFu;
        }
    }
}

// ---------------- pass 2: segment -> per-node buckets ----------------
__global__ __launch_bounds__(256) void k_scat(const unsigned* __restrict__ pairs,
                                              const int* __restrict__ cursor,
                                              int* __restrict__ cnt,
                                              int* __restrict__ esrc) {
    __shared__ int lcnt[112];
    const int bin = blockIdx.x >> 2;
    const int sub = blockIdx.x & 3;
    const int jl0 = sub * 112;
    const int jl1 = (jl0 + 112 < BINW) ? jl0 + 112 : BINW;   // sub3: 336..400
    const int nloc = jl1 - jl0;
    if (threadIdx.x < nloc) lcnt[threadIdx.x] = 0;
    __syncthreads();

    int n = cursor[bin]; if (n > SEGCAP) n = SEGCAP;
    const unsigned* seg = pairs + (size_t)bin * SEGCAP;
    for (int k = threadIdx.x; k < n; k += 256) {
        unsigned pr = seg[k];
        if ((int)pr < 0) continue;         // sentinel
        int jl = (int)(pr >> 17);
        if (jl < jl0 || jl >= jl1) continue;
        int i = (int)(pr & 0x1FFFFu);
        int p = atomicAdd(&lcnt[jl - jl0], 1);
        if (p < CAP) esrc[((size_t)(bin * BINW + jl)) * CAP + p] = i;
    }
    __syncthreads();
    if (threadIdx.x < nloc) cnt[bin * BINW + jl0 + threadIdx.x] = lcnt[threadIdx.x];
}

// ---------------- h = X@W (bf16 out) + s,t ----------------
// One 64-row tile per block. 16 lane-slots x 4 rows/thread: per k4 step,
// 8 ds_read_b128 feed 64 FMAs (best LDS amortization). xr padded to 17
// float4 -> 4-row stride = 272 dwords = 16 mod 32: 2-way conflict (free).
// NO launch_bounds min (r8's forced 64-VGPR cap caused 1 GB scratch spill);
// #pragma unroll 2 keeps live temps ~100 VGPR instead of full-unroll 252.
__global__ __launch_bounds__(256) void k_mm(const float4* __restrict__ X4,
                                            const float4* __restrict__ W4,
                                            const float* __restrict__ att,
                                            ushort4* __restrict__ hb,
                                            float* __restrict__ s,
                                            float* __restrict__ t) {
    __shared__ float4 Wl[64][16];    // Wl[k][q] = W[k][4q..4q+3]
    __shared__ float4 xr[64][17];    // 64 staged rows, padded
    const int tid  = threadIdx.x;
    const int lane = tid & 63;
    const int q    = lane & 15;
    const int slot = ((tid >> 6) << 2) | (lane >> 4);   // 0..15
    const int r0   = blockIdx.x * 64;

    for (int idx = tid; idx < 1024; idx += 256)
        Wl[idx >> 4][idx & 15] = W4[idx];
#pragma unroll
    for (int u = 0; u < 4; ++u) {
        int idx = u * 256 + tid;
        int row = r0 + (idx >> 4);
        xr[idx >> 4][idx & 15] = (row < NN) ? X4[(size_t)row * 16 + (idx & 15)]
                                            : make_float4(0.f, 0.f, 0.f, 0.f);
    }
    __syncthreads();

    const int rbase = slot * 4;
    float4 acc0 = {0,0,0,0}, acc1 = {0,0,0,0}, acc2 = {0,0,0,0}, acc3 = {0,0,0,0};
#pragma unroll 2
    for (int k4 = 0; k4 < 16; ++k4) {
        float4 w0 = Wl[k4 * 4 + 0][q];
        float4 w1 = Wl[k4 * 4 + 1][q];
        float4 w2 = Wl[k4 * 4 + 2][q];
        float4 w3 = Wl[k4 * 4 + 3][q];
        float4 x0 = xr[rbase + 0][k4];
        float4 x1 = xr[rbase + 1][k4];
        float4 x2 = xr[rbase + 2][k4];
        float4 x3 = xr[rbase + 3][k4];
        FMA4(acc0, x0.x, w0) FMA4(acc0, x0.y, w1) FMA4(acc0, x0.z, w2) FMA4(acc0, x0.w, w3)
        FMA4(acc1, x1.x, w0) FMA4(acc1, x1.y, w1) FMA4(acc1, x1.z, w2) FMA4(acc1, x1.w, w3)
        FMA4(acc2, x2.x, w0) FMA4(acc2, x2.y, w1) FMA4(acc2, x2.z, w2) FMA4(acc2, x2.w, w3)
        FMA4(acc3, x3.x, w0) FMA4(acc3, x3.y, w1) FMA4(acc3, x3.z, w2) FMA4(acc3, x3.w, w3)
    }

    const float4 ai = ((const float4*)att)[q];
    const float4 aj = ((const float4*)att)[16 + q];
    float4 accs[4] = {acc0, acc1, acc2, acc3};
#pragma unroll
    for (int rr = 0; rr < 4; ++rr) {
        int row = r0 + rbase + rr;
        if (row >= NN) continue;
        float4 a = accs[rr];
        ushort4 hv;
        hv.x = f2bf(a.x); hv.y = f2bf(a.y); hv.z = f2bf(a.z); hv.w = f2bf(a.w);
        hb[(size_t)row * 16 + q] = hv;
        float ps = a.x * ai.x + a.y * ai.y + a.z * ai.z + a.w * ai.w;
        float pt = a.x * aj.x + a.y * aj.y + a.z * aj.z + a.w * aj.w;
#pragma unroll
        for (int off = 1; off < 16; off <<= 1) {
            ps += __shfl_xor(ps, off);
            pt += __shfl_xor(pt, off);
        }
        if (q == 0) { s[row] = ps; t[row] = pt; }
    }
}

// ---------------- gather-softmax-aggregate ----------------
// 4 nodes/wave, 16 lanes x 4 dims (bf16 gathers, 128 B/edge).
// No max subtraction: |alpha| <= ~3, exp is exact-safe in f32.
__global__ __launch_bounds__(256) void k_gat(const ushort4* __restrict__ hb,
                                             const int* __restrict__ cnt,
                                             const int* __restrict__ esrc,
                                             const float* __restrict__ s,
                                             const float* __restrict__ t,
                                             const float* __restrict__ bias,
                                             float4* __restrict__ g4) {
    const int tid  = threadIdx.x;
    const int lane = tid & 63;
    const int w    = tid >> 6;
    const int q    = lane & 15;
    const int sub  = lane >> 4;
    const int j    = blockIdx.x * 16 + w * 4 + sub;   // 6250*16 = 100000 exact
    const int lsrc = sub * 16;

    const float sj = s[j];
    int deg = __builtin_nontemporal_load(&cnt[j]); if (deg > CAP) deg = CAP;
    const int base = j * CAP;

    // parallel edge phase: lane q handles edges q, q+16, q+32, q+48 of its node
    int   sc[4] = {0, 0, 0, 0};
    float ev[4] = {0.f, 0.f, 0.f, 0.f};
#pragma unroll
    for (int u = 0; u < 4; ++u) {
        int e = q + u * 16;
        if (e < deg) {
            int srcn = __builtin_nontemporal_load(&esrc[base + e]);
            sc[u] = srcn;
            ev[u] = expf(leaky(sj + t[srcn]));
        }
    }
    float den = ev[0] + ev[1] + ev[2] + ev[3];
#pragma unroll
    for (int off = 1; off < 16; off <<= 1) den += __shfl_xor(den, off);

    // self loop
    float evs = expf(leaky(sj + t[j]));
    den += evs;
    float4 hj = ldh(hb, (size_t)j * 16 + q);
    float4 acc;
    acc.x = evs * hj.x; acc.y = evs * hj.y; acc.z = evs * hj.z; acc.w = evs * hj.w;

    // serial accumulate: 4 independent chains per wave, loads batched 4-deep
#pragma unroll
    for (int u = 0; u < 4; ++u) {
        if (!__any(deg > u * 16)) break;
#pragma unroll
        for (int kk = 0; kk < 16; kk += 4) {
            int e0 = u * 16 + kk;
            if (!__any(deg > e0)) break;
            int   sA = __shfl(sc[u], lsrc + kk + 0);
            int   sB = __shfl(sc[u], lsrc + kk + 1);
            int   sC = __shfl(sc[u], lsrc + kk + 2);
            int   sD = __shfl(sc[u], lsrc + kk + 3);
            float eA = __shfl(ev[u], lsrc + kk + 0);
            float eB = __shfl(ev[u], lsrc + kk + 1);
            float eC = __shfl(ev[u], lsrc + kk + 2);
            float eD = __shfl(ev[u], lsrc + kk + 3);
            float4 vA = {0,0,0,0}, vB = {0,0,0,0}, vC = {0,0,0,0}, vD = {0,0,0,0};
            if (e0 + 0 < deg) vA = ldh(hb, (size_t)sA * 16 + q);
            if (e0 + 1 < deg) vB = ldh(hb, (size_t)sB * 16 + q);
            if (e0 + 2 < deg) vC = ldh(hb, (size_t)sC * 16 + q);
            if (e0 + 3 < deg) vD = ldh(hb, (size_t)sD * 16 + q);
            FMA4(acc, eA, vA) FMA4(acc, eB, vB) FMA4(acc, eC, vC) FMA4(acc, eD, vD)
        }
    }

    float4 bv = ((const float4*)bias)[q];
    float inv = 1.0f / (den + 1e-16f);
    float4 v;
    v.x = acc.x * inv + bv.x; v.y = acc.y * inv + bv.y;
    v.z = acc.z * inv + bv.z; v.w = acc.w * inv + bv.w;
    float sq = v.x * v.x + v.y * v.y + v.z * v.z + v.w * v.w;
#pragma unroll
    for (int off = 1; off < 16; off <<= 1) sq += __shfl_xor(sq, off);
    float nm = fmaxf(sqrtf(sq), 1e-12f);
    float4 o;
    o.x = v.x / nm; o.y = v.y / nm; o.z = v.z / nm; o.w = v.w / nm;
    g4[(size_t)j * 16 + q] = o;
}

// ---------------- scores + reg loss ----------------
__global__ __launch_bounds__(256) void k5_score(const float4* __restrict__ X4,
                                                const float4* __restrict__ g4,
                                                const int* __restrict__ user,
                                                const int* __restrict__ pos,
                                                const int* __restrict__ neg,
                                                const int* __restrict__ posr,
                                                const int* __restrict__ negr,
                                                float* __restrict__ out) {
    const int tid  = threadIdx.x;
    const int lane = tid & 63;
    const int q    = lane & 15;
    const int sub  = lane >> 4;
    const int b    = blockIdx.x * 16 + (tid >> 6) * 4 + sub;

    int u = user[b], p = pos[b], n = neg[b], pr = posr[b], nr = negr[b];
    float4 xu = X4[(size_t)u * 16 + q],  gu = g4[(size_t)u * 16 + q];
    float4 xp = X4[(size_t)p * 16 + q],  gp = g4[(size_t)p * 16 + q];
    float4 xn = X4[(size_t)n * 16 + q],  gn = g4[(size_t)n * 16 + q];
    float4 xq = X4[(size_t)pr * 16 + q], gq = g4[(size_t)pr * 16 + q];
    float4 xm = X4[(size_t)nr * 16 + q], gm = g4[(size_t)nr * 16 + q];

#define DOT(a, c) (a.x * c.x + a.y * c.y + a.z * c.z + a.w * c.w)
    float dp = DOT(xu, xp) + DOT(gu, gp);
    float dn = DOT(xu, xn) + DOT(gu, gn);
    float dq = DOT(xu, xq) + DOT(gu, gq);
    float dm = DOT(xu, xm) + DOT(gu, gm);
    float rg = 0.5f    * (DOT(xu, xu) + DOT(gu, gu) + DOT(xp, xp) + DOT(gp, gp)
                        + DOT(xn, xn) + DOT(gn, gn))
             + 0.0005f * (DOT(xq, xq) + DOT(gq, gq) + DOT(xm, xm) + DOT(gm, gm));
#undef DOT
#pragma unroll
    for (int off = 1; off < 16; off <<= 1) {
        dp += __shfl_xor(dp, off);
        dn += __shfl_xor(dn, off);
        dq += __shfl_xor(dq, off);
        dm += __shfl_xor(dm, off);
    }
    if (q == 0) {
        out[b]      = dp + 0.1f * dq;
        out[BB + b] = dn + 0.1f * dm;
    }
#pragma unroll
    for (int off = 16; off < 64; off <<= 1) rg += __shfl_xor(rg, off);
#pragma unroll
    for (int off = 1; off < 16; off <<= 1) rg += __shfl_xor(rg, off);
    if (lane == 0) unsafeAtomicAdd(&out[2 * BB], rg);
}

extern "C" void kernel_launch(void* const* d_in, const int* in_sizes, int n_in,
                              void* d_out, int out_size, void* d_ws, size_t ws_size,
                              hipStream_t stream) {
    const float* X    = (const float*)d_in[0];
    const float* W    = (const float*)d_in[1];
    const float* att  = (const float*)d_in[2];
    const float* bias = (const float*)d_in[3];
    const int* edges  = (const int*)d_in[4];
    const int* user   = (const int*)d_in[5];
    const int* pos    = (const int*)d_in[6];
    const int* neg    = (const int*)d_in[7];
    const int* posr   = (const int*)d_in[8];
    const int* negr   = (const int*)d_in[9];
    float* out = (float*)d_out;

    ushort4*  hb     = (ushort4*)d_ws;                       // NN*16 ushort4 (bf16 h)
    float4*   g4     = (float4*)(hb + (size_t)NN * 16);      // NN*16 float4
    float*    s      = (float*)(g4 + (size_t)NN * 16);       // NN
    float*    t      = s + NN;                               // NN
    int*      cnt    = (int*)(t + NN);                       // NN
    int*      esrc   = cnt + NN;                             // NN*CAP
    unsigned* pairs  = (unsigned*)(esrc + (size_t)NN * CAP); // NBIN*SEGCAP
    int*      cursor = (int*)(pairs + (size_t)NBIN * SEGCAP);// NBIN

    hipMemsetAsync(cursor, 0, 256 * sizeof(int), stream);
    hipMemsetAsync(out, 0, (size_t)(2 * BB + 1) * sizeof(float), stream);

    k_bin<<<NP1, 256, 0, stream>>>(edges, cursor, pairs);
    k_scat<<<NBIN * 4, 256, 0, stream>>>(pairs, cursor, cnt, esrc);
    k_mm<<<NMMB, 256, 0, stream>>>((const float4*)X, (const float4*)W, att, hb, s, t);
    k_gat<<<6250, 256, 0, stream>>>(hb, cnt, esrc, s, t, bias, g4);
    k5_score<<<256, 256, 0, stream>>>((const float4*)X, g4, user, pos, neg, posr, negr, out);
}

// Round 10
// 144.297 us; speedup vs baseline: 3.0336x; 1.0375x over previous
//
#include <hip/hip_runtime.h>

#define NN 100000
#define SE 16
#define NE 1600000        // NN*SE
#define BB 4096
#define CAP 64            // per-node bucket capacity (deg ~ Poisson(16))
#define NBIN 250          // fine bins of 400 nodes: 250*400 = 100000 exactly
#define BINW 400
#define SEGCAP 12288      // per-bin segment capacity (avg 6400 + align waste ~3000)
#define NP1 391           // ceil(NE / 4096)
#define NMMB 1563         // ceil(NN/64) one 64-row tile per block

__device__ __forceinline__ float leaky(float x) { return x > 0.0f ? x : 0.2f * x; }

__device__ __forceinline__ unsigned short f2bf(float f) {     // RNE f32 -> bf16
    unsigned u = __float_as_uint(f);
    u += 0x7fffu + ((u >> 16) & 1u);
    return (unsigned short)(u >> 16);
}
__device__ __forceinline__ float bf2f(unsigned short h) {
    return __uint_as_float(((unsigned)h) << 16);
}
__device__ __forceinline__ float4 cvt4(ushort4 v) {
    float4 r;
    r.x = bf2f(v.x); r.y = bf2f(v.y); r.z = bf2f(v.z); r.w = bf2f(v.w);
    return r;
}
__device__ __forceinline__ float4 ldh(const ushort4* __restrict__ hb, size_t idx) {
    return cvt4(hb[idx]);
}

#define FMA4(a, sx, wv) \
    a.x = fmaf(sx, wv.x, a.x); a.y = fmaf(sx, wv.y, a.y); \
    a.z = fmaf(sx, wv.z, a.z); a.w = fmaf(sx, wv.w, a.w);

// ---------------- pass 1: bin edges by dst into 250 segments ----------------
__global__ __launch_bounds__(256) void k_bin(const int* __restrict__ edges,
                                             int* __restrict__ cursor,
                                             unsigned* __restrict__ pairs) {
    __shared__ int hist[NBIN];
    __shared__ int gbase[NBIN];
    __shared__ int resv[NBIN];
    __shared__ int off[NBIN];
    const int tid = threadIdx.x;
    const int e0  = blockIdx.x * 4096;

    if (tid < NBIN) hist[tid] = 0;
    __syncthreads();

    int pb[16];   // packed pair
    int bn[16];   // bin (-1 = invalid)
#pragma unroll
    for (int it = 0; it < 16; ++it) {
        int e = e0 + it * 256 + tid;
        int b = -1, pr = 0;
        if (e < NE) {
            int j = __builtin_nontemporal_load(&edges[e]);
            int i = e >> 4;
            if (j != i) {
                b  = j / BINW;
                pr = ((j - b * BINW) << 17) | i;
            }
        }
        bn[it] = b; pb[it] = pr;
        if (b >= 0) atomicAdd(&hist[b], 1);
    }
    __syncthreads();

    if (tid < NBIN) {
        int c   = hist[tid];
        int res = (c + 15) & ~15;          // line-aligned reservation
        int gb  = res ? atomicAdd(&cursor[tid], res) : 0;
        if (gb + res > SEGCAP) gb = SEGCAP;   // overflow guard (statistically never)
        gbase[tid] = gb; resv[tid] = res; off[tid] = 0;
    }
    __syncthreads();

#pragma unroll
    for (int it = 0; it < 16; ++it) {
        int b = bn[it];
        if (b >= 0) {
            int o   = atomicAdd(&off[b], 1);
            int pos = gbase[b] + o;
            if (pos < SEGCAP) pairs[(size_t)b * SEGCAP + pos] = (unsigned)pb[it];
        }
    }
    __syncthreads();

    if (tid < NBIN) {                      // sentinel-fill alignment gap
        int base = gbase[tid];
        for (int k = hist[tid]; k < resv[tid]; ++k) {
            int pos = base + k;
            if (pos < SEGCAP) pairs[(size_t)tid * SEGCAP + pos] = 0xFFFFFFFFu;
        }
    }
}

// ---------------- pass 2: segment -> per-node buckets ----------------
__global__ __launch_bounds__(256) void k_scat(const unsigned* __restrict__ pairs,
                                              const int* __restrict__ cursor,
                                              int* __restrict__ cnt,
                                              int* __restrict__ esrc) {
    __shared__ int lcnt[112];
    const int bin = blockIdx.x >> 2;
    const int sub = blockIdx.x & 3;
    const int jl0 = sub * 112;
    const int jl1 = (jl0 + 112 < BINW) ? jl0 + 112 : BINW;   // sub3: 336..400
    const int nloc = jl1 - jl0;
    if (threadIdx.x < nloc) lcnt[threadIdx.x] = 0;
    __syncthreads();

    int n = cursor[bin]; if (n > SEGCAP) n = SEGCAP;
    const unsigned* seg = pairs + (size_t)bin * SEGCAP;
    for (int k = threadIdx.x; k < n; k += 256) {
        unsigned pr = seg[k];
        if ((int)pr < 0) continue;         // sentinel
        int jl = (int)(pr >> 17);
        if (jl < jl0 || jl >= jl1) continue;
        int i = (int)(pr & 0x1FFFFu);
        int p = atomicAdd(&lcnt[jl - jl0], 1);
        if (p < CAP) esrc[((size_t)(bin * BINW + jl)) * CAP + p] = i;
    }
    __syncthreads();
    if (threadIdx.x < nloc) cnt[bin * BINW + jl0 + threadIdx.x] = lcnt[threadIdx.x];
}

// ---------------- h = X@W (bf16 out) + s,t ----------------
// One 64-row tile per block. 16 lane-slots x 4 rows/thread. xr padded to 17
// float4 -> 2-way bank conflict only (free). No launch_bounds min (r8 spill
// lesson); #pragma unroll 2 keeps live temps ~100 VGPR.
__global__ __launch_bounds__(256) void k_mm(const float4* __restrict__ X4,
                                            const float4* __restrict__ W4,
                                            const float* __restrict__ att,
                                            ushort4* __restrict__ hb,
                                            float* __restrict__ s,
                                            float* __restrict__ t) {
    __shared__ float4 Wl[64][16];    // Wl[k][q] = W[k][4q..4q+3]
    __shared__ float4 xr[64][17];    // 64 staged rows, padded
    const int tid  = threadIdx.x;
    const int lane = tid & 63;
    const int q    = lane & 15;
    const int slot = ((tid >> 6) << 2) | (lane >> 4);   // 0..15
    const int r0   = blockIdx.x * 64;

    for (int idx = tid; idx < 1024; idx += 256)
        Wl[idx >> 4][idx & 15] = W4[idx];
#pragma unroll
    for (int u = 0; u < 4; ++u) {
        int idx = u * 256 + tid;
        int row = r0 + (idx >> 4);
        xr[idx >> 4][idx & 15] = (row < NN) ? X4[(size_t)row * 16 + (idx & 15)]
                                            : make_float4(0.f, 0.f, 0.f, 0.f);
    }
    __syncthreads();

    const int rbase = slot * 4;
    float4 acc0 = {0,0,0,0}, acc1 = {0,0,0,0}, acc2 = {0,0,0,0}, acc3 = {0,0,0,0};
#pragma unroll 2
    for (int k4 = 0; k4 < 16; ++k4) {
        float4 w0 = Wl[k4 * 4 + 0][q];
        float4 w1 = Wl[k4 * 4 + 1][q];
        float4 w2 = Wl[k4 * 4 + 2][q];
        float4 w3 = Wl[k4 * 4 + 3][q];
        float4 x0 = xr[rbase + 0][k4];
        float4 x1 = xr[rbase + 1][k4];
        float4 x2 = xr[rbase + 2][k4];
        float4 x3 = xr[rbase + 3][k4];
        FMA4(acc0, x0.x, w0) FMA4(acc0, x0.y, w1) FMA4(acc0, x0.z, w2) FMA4(acc0, x0.w, w3)
        FMA4(acc1, x1.x, w0) FMA4(acc1, x1.y, w1) FMA4(acc1, x1.z, w2) FMA4(acc1, x1.w, w3)
        FMA4(acc2, x2.x, w0) FMA4(acc2, x2.y, w1) FMA4(acc2, x2.z, w2) FMA4(acc2, x2.w, w3)
        FMA4(acc3, x3.x, w0) FMA4(acc3, x3.y, w1) FMA4(acc3, x3.z, w2) FMA4(acc3, x3.w, w3)
    }

    const float4 ai = ((const float4*)att)[q];
    const float4 aj = ((const float4*)att)[16 + q];
    float4 accs[4] = {acc0, acc1, acc2, acc3};
#pragma unroll
    for (int rr = 0; rr < 4; ++rr) {
        int row = r0 + rbase + rr;
        if (row >= NN) continue;
        float4 a = accs[rr];
        ushort4 hv;
        hv.x = f2bf(a.x); hv.y = f2bf(a.y); hv.z = f2bf(a.z); hv.w = f2bf(a.w);
        hb[(size_t)row * 16 + q] = hv;
        float ps = a.x * ai.x + a.y * ai.y + a.z * ai.z + a.w * ai.w;
        float pt = a.x * aj.x + a.y * aj.y + a.z * aj.z + a.w * aj.w;
#pragma unroll
        for (int off = 1; off < 16; off <<= 1) {
            ps += __shfl_xor(ps, off);
            pt += __shfl_xor(pt, off);
        }
        if (q == 0) { s[row] = ps; t[row] = pt; }
    }
}

// ---------------- gather-softmax-aggregate ----------------
// 4 nodes/wave, 16 lanes x 4 dims. r10: full 16-edge load batch (16
// outstanding gathers/lane, vb[] statically indexed) + 4 independent
// accumulator chains -> 4x the memory-level parallelism of the r9 4-deep
// batches. Loads are unconditional (invalid edges read h[0], scaled by
// ev=0) -> no divergence around loads.
__global__ __launch_bounds__(256) void k_gat(const ushort4* __restrict__ hb,
                                             const int* __restrict__ cnt,
                                             const int* __restrict__ esrc,
                                             const float* __restrict__ s,
                                             const float* __restrict__ t,
                                             const float* __restrict__ bias,
                                             float4* __restrict__ g4) {
    const int tid  = threadIdx.x;
    const int lane = tid & 63;
    const int w    = tid >> 6;
    const int q    = lane & 15;
    const int sub  = lane >> 4;
    const int j    = blockIdx.x * 16 + w * 4 + sub;   // 6250*16 = 100000 exact
    const int lsrc = sub * 16;

    const float sj = s[j];
    int deg = __builtin_nontemporal_load(&cnt[j]); if (deg > CAP) deg = CAP;
    const int base = j * CAP;

    // parallel edge phase: lane q handles edges q, q+16, q+32, q+48 of its node
    int   sc[4];
    float ev[4];
#pragma unroll
    for (int u = 0; u < 4; ++u) {
        int e = q + u * 16;
        int srcn = 0; float evv = 0.f;
        if (e < deg) {
            srcn = __builtin_nontemporal_load(&esrc[base + e]);
            evv  = expf(leaky(sj + t[srcn]));
        }
        sc[u] = srcn; ev[u] = evv;
    }
    float den = ev[0] + ev[1] + ev[2] + ev[3];
#pragma unroll
    for (int off = 1; off < 16; off <<= 1) den += __shfl_xor(den, off);

    // self loop
    float evs = expf(leaky(sj + t[j]));
    den += evs;
    float4 hj = ldh(hb, (size_t)j * 16 + q);
    float4 a0, a1, a2, a3;
    a0.x = evs * hj.x; a0.y = evs * hj.y; a0.z = evs * hj.z; a0.w = evs * hj.w;
    a1 = make_float4(0.f, 0.f, 0.f, 0.f);
    a2 = a1; a3 = a1;

#pragma unroll
    for (int u = 0; u < 4; ++u) {
        if (!__any(deg > u * 16)) break;
        ushort4 vb[16];
#pragma unroll
        for (int kk = 0; kk < 16; ++kk) {
            int sK = __shfl(sc[u], lsrc + kk);
            vb[kk] = hb[(size_t)sK * 16 + q];
        }
#define STEP(kk, A) { float eK = __shfl(ev[u], lsrc + kk); \
                      float4 vv = cvt4(vb[kk]); FMA4(A, eK, vv) }
        STEP(0,  a0) STEP(1,  a1) STEP(2,  a2) STEP(3,  a3)
        STEP(4,  a0) STEP(5,  a1) STEP(6,  a2) STEP(7,  a3)
        STEP(8,  a0) STEP(9,  a1) STEP(10, a2) STEP(11, a3)
        STEP(12, a0) STEP(13, a1) STEP(14, a2) STEP(15, a3)
#undef STEP
    }
    float4 acc;
    acc.x = (a0.x + a1.x) + (a2.x + a3.x);
    acc.y = (a0.y + a1.y) + (a2.y + a3.y);
    acc.z = (a0.z + a1.z) + (a2.z + a3.z);
    acc.w = (a0.w + a1.w) + (a2.w + a3.w);

    float4 bv = ((const float4*)bias)[q];
    float inv = 1.0f / (den + 1e-16f);
    float4 v;
    v.x = acc.x * inv + bv.x; v.y = acc.y * inv + bv.y;
    v.z = acc.z * inv + bv.z; v.w = acc.w * inv + bv.w;
    float sq = v.x * v.x + v.y * v.y + v.z * v.z + v.w * v.w;
#pragma unroll
    for (int off = 1; off < 16; off <<= 1) sq += __shfl_xor(sq, off);
    float nm = fmaxf(sqrtf(sq), 1e-12f);
    float4 o;
    o.x = v.x / nm; o.y = v.y / nm; o.z = v.z / nm; o.w = v.w / nm;
    g4[(size_t)j * 16 + q] = o;
}

// ---------------- scores + reg loss ----------------
__global__ __launch_bounds__(256) void k5_score(const float4* __restrict__ X4,
                                                const float4* __restrict__ g4,
                                                const int* __restrict__ user,
                                                const int* __restrict__ pos,
                                                const int* __restrict__ neg,
                                                const int* __restrict__ posr,
                                                const int* __restrict__ negr,
                                                float* __restrict__ out) {
    const int tid  = threadIdx.x;
    const int lane = tid & 63;
    const int q    = lane & 15;
    const int sub  = lane >> 4;
    const int b    = blockIdx.x * 16 + (tid >> 6) * 4 + sub;

    int u = user[b], p = pos[b], n = neg[b], pr = posr[b], nr = negr[b];
    float4 xu = X4[(size_t)u * 16 + q],  gu = g4[(size_t)u * 16 + q];
    float4 xp = X4[(size_t)p * 16 + q],  gp = g4[(size_t)p * 16 + q];
    float4 xn = X4[(size_t)n * 16 + q],  gn = g4[(size_t)n * 16 + q];
    float4 xq = X4[(size_t)pr * 16 + q], gq = g4[(size_t)pr * 16 + q];
    float4 xm = X4[(size_t)nr * 16 + q], gm = g4[(size_t)nr * 16 + q];

#define DOT(a, c) (a.x * c.x + a.y * c.y + a.z * c.z + a.w * c.w)
    float dp = DOT(xu, xp) + DOT(gu, gp);
    float dn = DOT(xu, xn) + DOT(gu, gn);
    float dq = DOT(xu, xq) + DOT(gu, gq);
    float dm = DOT(xu, xm) + DOT(gu, gm);
    float rg = 0.5f    * (DOT(xu, xu) + DOT(gu, gu) + DOT(xp, xp) + DOT(gp, gp)
                        + DOT(xn, xn) + DOT(gn, gn))
             + 0.0005f * (DOT(xq, xq) + DOT(gq, gq) + DOT(xm, xm) + DOT(gm, gm));
#undef DOT
#pragma unroll
    for (int off = 1; off < 16; off <<= 1) {
        dp += __shfl_xor(dp, off);
        dn += __shfl_xor(dn, off);
        dq += __shfl_xor(dq, off);
        dm += __shfl_xor(dm, off);
    }
    if (q == 0) {
        out[b]      = dp + 0.1f * dq;
        out[BB + b] = dn + 0.1f * dm;
    }
#pragma unroll
    for (int off = 16; off < 64; off <<= 1) rg += __shfl_xor(rg, off);
#pragma unroll
    for (int off = 1; off < 16; off <<= 1) rg += __shfl_xor(rg, off);
    if (lane == 0) unsafeAtomicAdd(&out[2 * BB], rg);
}

extern "C" void kernel_launch(void* const* d_in, const int* in_sizes, int n_in,
                              void* d_out, int out_size, void* d_ws, size_t ws_size,
                              hipStream_t stream) {
    const float* X    = (const float*)d_in[0];
    const float* W    = (const float*)d_in[1];
    const float* att  = (const float*)d_in[2];
    const float* bias = (const float*)d_in[3];
    const int* edges  = (const int*)d_in[4];
    const int* user   = (const int*)d_in[5];
    const int* pos    = (const int*)d_in[6];
    const int* neg    = (const int*)d_in[7];
    const int* posr   = (const int*)d_in[8];
    const int* negr   = (const int*)d_in[9];
    float* out = (float*)d_out;

    ushort4*  hb     = (ushort4*)d_ws;                       // NN*16 ushort4 (bf16 h)
    float4*   g4     = (float4*)(hb + (size_t)NN * 16);      // NN*16 float4
    float*    s      = (float*)(g4 + (size_t)NN * 16);       // NN
    float*    t      = s + NN;                               // NN
    int*      cnt    = (int*)(t + NN);                       // NN
    int*      esrc   = cnt + NN;                             // NN*CAP
    unsigned* pairs  = (unsigned*)(esrc + (size_t)NN * CAP); // NBIN*SEGCAP
    int*      cursor = (int*)(pairs + (size_t)NBIN * SEGCAP);// NBIN

    hipMemsetAsync(cursor, 0, 256 * sizeof(int), stream);
    hipMemsetAsync(out, 0, (size_t)(2 * BB + 1) * sizeof(float), stream);

    k_bin<<<NP1, 256, 0, stream>>>(edges, cursor, pairs);
    k_scat<<<NBIN * 4, 256, 0, stream>>>(pairs, cursor, cnt, esrc);
    k_mm<<<NMMB, 256, 0, stream>>>((const float4*)X, (const float4*)W, att, hb, s, t);
    k_gat<<<6250, 256, 0, stream>>>(hb, cnt, esrc, s, t, bias, g4);
    k5_score<<<256, 256, 0, stream>>>((const float4*)X, g4, user, pos, neg, posr, negr, out);
}

// Round 11
// 89.262 us; speedup vs baseline: 4.9039x; 1.6166x over previous
//
#include <hip/hip_runtime.h>

#define NN 100000
#define SE 16
#define NE 1600000        // NN*SE
#define BB 4096
#define CAP 64            // per-node bucket capacity (deg ~ Poisson(16))
#define NMMB 1563         // ceil(NN/64) one 64-row tile per block
#define NLIST 20480       // 5*BB (upper bound on needed nodes)
#define NGB 1280          // NLIST/16 k_gat blocks
#define BMW 3136          // bitmap words (ceil(NN/32)=3125, padded)

__device__ __forceinline__ float leaky(float x) { return x > 0.0f ? x : 0.2f * x; }

__device__ __forceinline__ unsigned short f2bf(float f) {     // RNE f32 -> bf16
    unsigned u = __float_as_uint(f);
    u += 0x7fffu + ((u >> 16) & 1u);
    return (unsigned short)(u >> 16);
}
__device__ __forceinline__ float bf2f(unsigned short h) {
    return __uint_as_float(((unsigned)h) << 16);
}
__device__ __forceinline__ float4 cvt4(ushort4 v) {
    float4 r;
    r.x = bf2f(v.x); r.y = bf2f(v.y); r.z = bf2f(v.z); r.w = bf2f(v.w);
    return r;
}
__device__ __forceinline__ float4 ldh(const ushort4* __restrict__ hb, size_t idx) {
    return cvt4(hb[idx]);
}

#define FMA4(a, sx, wv) \
    a.x = fmaf(sx, wv.x, a.x); a.y = fmaf(sx, wv.y, a.y); \
    a.z = fmaf(sx, wv.z, a.z); a.w = fmaf(sx, wv.w, a.w);

// ---------------- mark needed nodes (dsts actually consumed by k5) ----------------
// g is only ever read at the 5*4096 batch indices -> ~18.5K unique nodes of 100K.
// atomicOr returns old word: exactly-once append to the compact list.
__global__ __launch_bounds__(256) void k_mark(const int* __restrict__ user,
                                              const int* __restrict__ pos,
                                              const int* __restrict__ neg,
                                              const int* __restrict__ posr,
                                              const int* __restrict__ negr,
                                              unsigned* __restrict__ bitmap,
                                              int* __restrict__ listlen,
                                              int* __restrict__ list) {
    int tid = blockIdx.x * 256 + threadIdx.x;   // 80 blocks = 20480 exact
    int a = tid >> 12, e = tid & 4095;
    const int* arr = (a == 0) ? user : (a == 1) ? pos : (a == 2) ? neg
                   : (a == 3) ? posr : negr;
    int node = arr[e];
    unsigned bit = 1u << (node & 31);
    unsigned old = atomicOr(&bitmap[node >> 5], bit);
    if (!(old & bit)) {
        int p = atomicAdd(listlen, 1);
        list[p] = node;
    }
}

// ---------------- bucket build, dst-filtered single-pass scatter ----------------
// Only ~300K of 1.6M edges have a needed dst; dirty cnt/esrc footprint ~3 MB
// (L2-resident), so the r4/r6 scatter-churn problem doesn't apply. Bitmap is
// 12.5 KB -> L1-resident lookups. NT on the edge stream (read-once).
__global__ __launch_bounds__(256) void k_bucket(const int* __restrict__ edges,
                                                const unsigned* __restrict__ bitmap,
                                                int* __restrict__ cnt,
                                                int* __restrict__ esrc) {
    for (int e = blockIdx.x * 256 + threadIdx.x; e < NE; e += 2048 * 256) {
        int j = __builtin_nontemporal_load(&edges[e]);
        int i = e >> 4;
        if (j != i && ((bitmap[j >> 5] >> (j & 31)) & 1u)) {
            int p = atomicAdd(&cnt[j], 1);
            if (p < CAP) esrc[j * CAP + p] = i;
        }
    }
}

// ---------------- h = X@W (bf16 out) + s,t ----------------
// One 64-row tile per block. 16 lane-slots x 4 rows/thread. xr padded to 17
// float4 -> 2-way bank conflict only (free). No launch_bounds min (r8 spill
// lesson); #pragma unroll 2 keeps live temps ~100 VGPR.
__global__ __launch_bounds__(256) void k_mm(const float4* __restrict__ X4,
                                            const float4* __restrict__ W4,
                                            const float* __restrict__ att,
                                            ushort4* __restrict__ hb,
                                            float* __restrict__ s,
                                            float* __restrict__ t) {
    __shared__ float4 Wl[64][16];    // Wl[k][q] = W[k][4q..4q+3]
    __shared__ float4 xr[64][17];    // 64 staged rows, padded
    const int tid  = threadIdx.x;
    const int lane = tid & 63;
    const int q    = lane & 15;
    const int slot = ((tid >> 6) << 2) | (lane >> 4);   // 0..15
    const int r0   = blockIdx.x * 64;

    for (int idx = tid; idx < 1024; idx += 256)
        Wl[idx >> 4][idx & 15] = W4[idx];
#pragma unroll
    for (int u = 0; u < 4; ++u) {
        int idx = u * 256 + tid;
        int row = r0 + (idx >> 4);
        xr[idx >> 4][idx & 15] = (row < NN) ? X4[(size_t)row * 16 + (idx & 15)]
                                            : make_float4(0.f, 0.f, 0.f, 0.f);
    }
    __syncthreads();

    const int rbase = slot * 4;
    float4 acc0 = {0,0,0,0}, acc1 = {0,0,0,0}, acc2 = {0,0,0,0}, acc3 = {0,0,0,0};
#pragma unroll 2
    for (int k4 = 0; k4 < 16; ++k4) {
        float4 w0 = Wl[k4 * 4 + 0][q];
        float4 w1 = Wl[k4 * 4 + 1][q];
        float4 w2 = Wl[k4 * 4 + 2][q];
        float4 w3 = Wl[k4 * 4 + 3][q];
        float4 x0 = xr[rbase + 0][k4];
        float4 x1 = xr[rbase + 1][k4];
        float4 x2 = xr[rbase + 2][k4];
        float4 x3 = xr[rbase + 3][k4];
        FMA4(acc0, x0.x, w0) FMA4(acc0, x0.y, w1) FMA4(acc0, x0.z, w2) FMA4(acc0, x0.w, w3)
        FMA4(acc1, x1.x, w0) FMA4(acc1, x1.y, w1) FMA4(acc1, x1.z, w2) FMA4(acc1, x1.w, w3)
        FMA4(acc2, x2.x, w0) FMA4(acc2, x2.y, w1) FMA4(acc2, x2.z, w2) FMA4(acc2, x2.w, w3)
        FMA4(acc3, x3.x, w0) FMA4(acc3, x3.y, w1) FMA4(acc3, x3.z, w2) FMA4(acc3, x3.w, w3)
    }

    const float4 ai = ((const float4*)att)[q];
    const float4 aj = ((const float4*)att)[16 + q];
    float4 accs[4] = {acc0, acc1, acc2, acc3};
#pragma unroll
    for (int rr = 0; rr < 4; ++rr) {
        int row = r0 + rbase + rr;
        if (row >= NN) continue;
        float4 a = accs[rr];
        ushort4 hv;
        hv.x = f2bf(a.x); hv.y = f2bf(a.y); hv.z = f2bf(a.z); hv.w = f2bf(a.w);
        hb[(size_t)row * 16 + q] = hv;
        float ps = a.x * ai.x + a.y * ai.y + a.z * ai.z + a.w * ai.w;
        float pt = a.x * aj.x + a.y * aj.y + a.z * aj.z + a.w * aj.w;
#pragma unroll
        for (int off = 1; off < 16; off <<= 1) {
            ps += __shfl_xor(ps, off);
            pt += __shfl_xor(pt, off);
        }
        if (q == 0) { s[row] = ps; t[row] = pt; }
    }
}

// ---------------- gather-softmax-aggregate over the NEEDED list only ----------------
// 4 nodes/wave, 16 lanes x 4 dims. Full 16-edge load batch (16 outstanding
// gathers/lane) + 4 independent accumulator chains. Invalid subs (past llen)
// use node 0 addresses with ev=0 and skip all writes.
__global__ __launch_bounds__(256) void k_gat(const ushort4* __restrict__ hb,
                                             const int* __restrict__ cnt,
                                             const int* __restrict__ esrc,
                                             const float* __restrict__ s,
                                             const float* __restrict__ t,
                                             const float* __restrict__ bias,
                                             const int* __restrict__ listlen,
                                             const int* __restrict__ list,
                                             float4* __restrict__ g4) {
    const int llen = *listlen;
    if (blockIdx.x * 16 >= llen) return;
    const int tid  = threadIdx.x;
    const int lane = tid & 63;
    const int w    = tid >> 6;
    const int q    = lane & 15;
    const int sub  = lane >> 4;
    const int gn   = blockIdx.x * 16 + w * 4 + sub;
    const int j    = (gn < llen) ? list[gn] : -1;
    const int jj   = (j < 0) ? 0 : j;
    const int lsrc = sub * 16;

    const float sj = s[jj];
    int deg = (j < 0) ? 0 : cnt[jj];
    if (deg > CAP) deg = CAP;
    const int base = jj * CAP;

    // parallel edge phase: lane q handles edges q, q+16, q+32, q+48 of its node
    int   sc[4];
    float ev[4];
#pragma unroll
    for (int u = 0; u < 4; ++u) {
        int e = q + u * 16;
        int srcn = 0; float evv = 0.f;
        if (e < deg) {
            srcn = __builtin_nontemporal_load(&esrc[base + e]);
            evv  = expf(leaky(sj + t[srcn]));
        }
        sc[u] = srcn; ev[u] = evv;
    }
    float den = ev[0] + ev[1] + ev[2] + ev[3];
#pragma unroll
    for (int off = 1; off < 16; off <<= 1) den += __shfl_xor(den, off);

    // self loop
    float evs = expf(leaky(sj + t[jj]));
    den += evs;
    float4 hj = ldh(hb, (size_t)jj * 16 + q);
    float4 a0, a1, a2, a3;
    a0.x = evs * hj.x; a0.y = evs * hj.y; a0.z = evs * hj.z; a0.w = evs * hj.w;
    a1 = make_float4(0.f, 0.f, 0.f, 0.f);
    a2 = a1; a3 = a1;

#pragma unroll
    for (int u = 0; u < 4; ++u) {
        if (!__any(deg > u * 16)) break;
        ushort4 vb[16];
#pragma unroll
        for (int kk = 0; kk < 16; ++kk) {
            int sK = __shfl(sc[u], lsrc + kk);
            vb[kk] = hb[(size_t)sK * 16 + q];
        }
#define STEP(kk, A) { float eK = __shfl(ev[u], lsrc + kk); \
                      float4 vv = cvt4(vb[kk]); FMA4(A, eK, vv) }
        STEP(0,  a0) STEP(1,  a1) STEP(2,  a2) STEP(3,  a3)
        STEP(4,  a0) STEP(5,  a1) STEP(6,  a2) STEP(7,  a3)
        STEP(8,  a0) STEP(9,  a1) STEP(10, a2) STEP(11, a3)
        STEP(12, a0) STEP(13, a1) STEP(14, a2) STEP(15, a3)
#undef STEP
    }
    float4 acc;
    acc.x = (a0.x + a1.x) + (a2.x + a3.x);
    acc.y = (a0.y + a1.y) + (a2.y + a3.y);
    acc.z = (a0.z + a1.z) + (a2.z + a3.z);
    acc.w = (a0.w + a1.w) + (a2.w + a3.w);

    float4 bv = ((const float4*)bias)[q];
    float inv = 1.0f / (den + 1e-16f);
    float4 v;
    v.x = acc.x * inv + bv.x; v.y = acc.y * inv + bv.y;
    v.z = acc.z * inv + bv.z; v.w = acc.w * inv + bv.w;
    float sq = v.x * v.x + v.y * v.y + v.z * v.z + v.w * v.w;
#pragma unroll
    for (int off = 1; off < 16; off <<= 1) sq += __shfl_xor(sq, off);
    float nm = fmaxf(sqrtf(sq), 1e-12f);
    if (j >= 0) {
        float4 o;
        o.x = v.x / nm; o.y = v.y / nm; o.z = v.z / nm; o.w = v.w / nm;
        g4[(size_t)j * 16 + q] = o;
    }
}

// ---------------- scores + reg loss ----------------
__global__ __launch_bounds__(256) void k5_score(const float4* __restrict__ X4,
                                                const float4* __restrict__ g4,
                                                const int* __restrict__ user,
                                                const int* __restrict__ pos,
                                                const int* __restrict__ neg,
                                                const int* __restrict__ posr,
                                                const int* __restrict__ negr,
                                                float* __restrict__ out) {
    const int tid  = threadIdx.x;
    const int lane = tid & 63;
    const int q    = lane & 15;
    const int sub  = lane >> 4;
    const int b    = blockIdx.x * 16 + (tid >> 6) * 4 + sub;

    int u = user[b], p = pos[b], n = neg[b], pr = posr[b], nr = negr[b];
    float4 xu = X4[(size_t)u * 16 + q],  gu = g4[(size_t)u * 16 + q];
    float4 xp = X4[(size_t)p * 16 + q],  gp = g4[(size_t)p * 16 + q];
    float4 xn = X4[(size_t)n * 16 + q],  gn = g4[(size_t)n * 16 + q];
    float4 xq = X4[(size_t)pr * 16 + q], gq = g4[(size_t)pr * 16 + q];
    float4 xm = X4[(size_t)nr * 16 + q], gm = g4[(size_t)nr * 16 + q];

#define DOT(a, c) (a.x * c.x + a.y * c.y + a.z * c.z + a.w * c.w)
    float dp = DOT(xu, xp) + DOT(gu, gp);
    float dn = DOT(xu, xn) + DOT(gu, gn);
    float dq = DOT(xu, xq) + DOT(gu, gq);
    float dm = DOT(xu, xm) + DOT(gu, gm);
    float rg = 0.5f    * (DOT(xu, xu) + DOT(gu, gu) + DOT(xp, xp) + DOT(gp, gp)
                        + DOT(xn, xn) + DOT(gn, gn))
             + 0.0005f * (DOT(xq, xq) + DOT(gq, gq) + DOT(xm, xm) + DOT(gm, gm));
#undef DOT
#pragma unroll
    for (int off = 1; off < 16; off <<= 1) {
        dp += __shfl_xor(dp, off);
        dn += __shfl_xor(dn, off);
        dq += __shfl_xor(dq, off);
        dm += __shfl_xor(dm, off);
    }
    if (q == 0) {
        out[b]      = dp + 0.1f * dq;
        out[BB + b] = dn + 0.1f * dm;
    }
#pragma unroll
    for (int off = 16; off < 64; off <<= 1) rg += __shfl_xor(rg, off);
#pragma unroll
    for (int off = 1; off < 16; off <<= 1) rg += __shfl_xor(rg, off);
    if (lane == 0) unsafeAtomicAdd(&out[2 * BB], rg);
}

extern "C" void kernel_launch(void* const* d_in, const int* in_sizes, int n_in,
                              void* d_out, int out_size, void* d_ws, size_t ws_size,
                              hipStream_t stream) {
    const float* X    = (const float*)d_in[0];
    const float* W    = (const float*)d_in[1];
    const float* att  = (const float*)d_in[2];
    const float* bias = (const float*)d_in[3];
    const int* edges  = (const int*)d_in[4];
    const int* user   = (const int*)d_in[5];
    const int* pos    = (const int*)d_in[6];
    const int* neg    = (const int*)d_in[7];
    const int* posr   = (const int*)d_in[8];
    const int* negr   = (const int*)d_in[9];
    float* out = (float*)d_out;

    // layout: hb | g4 | s | t | [cnt | bitmap | listlen] (one memset) | list | esrc
    ushort4*  hb      = (ushort4*)d_ws;                      // NN*16 ushort4 (bf16 h)
    float4*   g4      = (float4*)(hb + (size_t)NN * 16);     // NN*16 float4
    float*    s       = (float*)(g4 + (size_t)NN * 16);      // NN
    float*    t       = s + NN;                              // NN
    int*      cnt     = (int*)(t + NN);                      // NN
    unsigned* bitmap  = (unsigned*)(cnt + NN);               // BMW
    int*      listlen = (int*)(bitmap + BMW);                // 16 (padded)
    int*      list    = listlen + 16;                        // NLIST
    int*      esrc    = list + NLIST;                        // NN*CAP

    hipMemsetAsync(cnt, 0, (size_t)(NN + BMW + 16) * sizeof(int), stream);
    hipMemsetAsync(out, 0, (size_t)(2 * BB + 1) * sizeof(float), stream);

    k_mark<<<80, 256, 0, stream>>>(user, pos, neg, posr, negr, bitmap, listlen, list);
    k_bucket<<<2048, 256, 0, stream>>>(edges, bitmap, cnt, esrc);
    k_mm<<<NMMB, 256, 0, stream>>>((const float4*)X, (const float4*)W, att, hb, s, t);
    k_gat<<<NGB, 256, 0, stream>>>(hb, cnt, esrc, s, t, bias, listlen, list, g4);
    k5_score<<<256, 256, 0, stream>>>((const float4*)X, g4, user, pos, neg, posr, negr, out);
}

// Round 12
// 85.426 us; speedup vs baseline: 5.1242x; 1.0449x over previous
//
#include <hip/hip_runtime.h>

#define NN 100000
#define SE 16
#define NE 1600000        // NN*SE
#define BB 4096
#define CAP 64            // per-node bucket capacity (deg ~ Poisson(16))
#define NMMB 1563         // ceil(NN/64) one 64-row tile per block
#define NLIST 20480       // 5*BB (upper bound on needed nodes)
#define NGB 1280          // NLIST/16 k_gat blocks
#define BMW 3136          // bitmap words (ceil(NN/32)=3125, padded)

__device__ __forceinline__ float leaky(float x) { return x > 0.0f ? x : 0.2f * x; }

__device__ __forceinline__ unsigned short f2bf(float f) {     // RNE f32 -> bf16
    unsigned u = __float_as_uint(f);
    u += 0x7fffu + ((u >> 16) & 1u);
    return (unsigned short)(u >> 16);
}
__device__ __forceinline__ float bf2f(unsigned short h) {
    return __uint_as_float(((unsigned)h) << 16);
}
__device__ __forceinline__ float4 cvt4(ushort4 v) {
    float4 r;
    r.x = bf2f(v.x); r.y = bf2f(v.y); r.z = bf2f(v.z); r.w = bf2f(v.w);
    return r;
}
__device__ __forceinline__ float4 ldh(const ushort4* __restrict__ hb, size_t idx) {
    return cvt4(hb[idx]);
}

#define FMA4(a, sx, wv) \
    a.x = fmaf(sx, wv.x, a.x); a.y = fmaf(sx, wv.y, a.y); \
    a.z = fmaf(sx, wv.z, a.z); a.w = fmaf(sx, wv.w, a.w);

// ---------------- zero the small state (replaces rocclr fill: 41 us -> ~2 us) ----------------
// bitmap 12.5 KB + listlen + out[2*BB] (the only atomicAdd target in out; the
// score slots are written unconditionally by k5). cnt is zeroed lazily in k_mark.
__global__ __launch_bounds__(256) void k_zero(unsigned* __restrict__ bitmap,
                                              int* __restrict__ listlen,
                                              float* __restrict__ out) {
    int i = blockIdx.x * 256 + threadIdx.x;
    if (i < BMW) bitmap[i] = 0u;
    if (i < 16) listlen[i] = 0;
    if (i == 0) out[2 * BB] = 0.0f;
}

// ---------------- mark needed nodes (dsts actually consumed by k5) ----------------
// atomicOr returns old word: exactly-once append; the winning thread also
// zeroes cnt[node] (store happens-before k_bucket via kernel boundary), so
// the 400 KB cnt memset is gone. Unmarked nodes' cnt is garbage, never read.
__global__ __launch_bounds__(256) void k_mark(const int* __restrict__ user,
                                              const int* __restrict__ pos,
                                              const int* __restrict__ neg,
                                              const int* __restrict__ posr,
                                              const int* __restrict__ negr,
                                              unsigned* __restrict__ bitmap,
                                              int* __restrict__ listlen,
                                              int* __restrict__ list,
                                              int* __restrict__ cnt) {
    int tid = blockIdx.x * 256 + threadIdx.x;   // 80 blocks = 20480 exact
    int a = tid >> 12, e = tid & 4095;
    const int* arr = (a == 0) ? user : (a == 1) ? pos : (a == 2) ? neg
                   : (a == 3) ? posr : negr;
    int node = arr[e];
    unsigned bit = 1u << (node & 31);
    unsigned old = atomicOr(&bitmap[node >> 5], bit);
    if (!(old & bit)) {
        cnt[node] = 0;
        int p = atomicAdd(listlen, 1);
        list[p] = node;
    }
}

// ---------------- bucket build, dst-filtered single-pass scatter ----------------
// Only ~300K of 1.6M edges have a needed dst; dirty cnt/esrc footprint ~5 MB
// (mostly L2-resident). Bitmap is 12.5 KB -> L1-resident lookups. NT on the
// edge stream (read-once).
__global__ __launch_bounds__(256) void k_bucket(const int* __restrict__ edges,
                                                const unsigned* __restrict__ bitmap,
                                                int* __restrict__ cnt,
                                                int* __restrict__ esrc) {
    for (int e = blockIdx.x * 256 + threadIdx.x; e < NE; e += 2048 * 256) {
        int j = __builtin_nontemporal_load(&edges[e]);
        int i = e >> 4;
        if (j != i && ((bitmap[j >> 5] >> (j & 31)) & 1u)) {
            int p = atomicAdd(&cnt[j], 1);
            if (p < CAP) esrc[j * CAP + p] = i;
        }
    }
}

// ---------------- h = X@W (bf16 out) + s,t ----------------
// One 64-row tile per block. 16 lane-slots x 4 rows/thread. xr padded to 17
// float4 -> 2-way bank conflict only (free). No launch_bounds min (r8 spill
// lesson); #pragma unroll 2 keeps live temps ~100 VGPR.
__global__ __launch_bounds__(256) void k_mm(const float4* __restrict__ X4,
                                            const float4* __restrict__ W4,
                                            const float* __restrict__ att,
                                            ushort4* __restrict__ hb,
                                            float* __restrict__ s,
                                            float* __restrict__ t) {
    __shared__ float4 Wl[64][16];    // Wl[k][q] = W[k][4q..4q+3]
    __shared__ float4 xr[64][17];    // 64 staged rows, padded
    const int tid  = threadIdx.x;
    const int lane = tid & 63;
    const int q    = lane & 15;
    const int slot = ((tid >> 6) << 2) | (lane >> 4);   // 0..15
    const int r0   = blockIdx.x * 64;

    for (int idx = tid; idx < 1024; idx += 256)
        Wl[idx >> 4][idx & 15] = W4[idx];
#pragma unroll
    for (int u = 0; u < 4; ++u) {
        int idx = u * 256 + tid;
        int row = r0 + (idx >> 4);
        xr[idx >> 4][idx & 15] = (row < NN) ? X4[(size_t)row * 16 + (idx & 15)]
                                            : make_float4(0.f, 0.f, 0.f, 0.f);
    }
    __syncthreads();

    const int rbase = slot * 4;
    float4 acc0 = {0,0,0,0}, acc1 = {0,0,0,0}, acc2 = {0,0,0,0}, acc3 = {0,0,0,0};
#pragma unroll 2
    for (int k4 = 0; k4 < 16; ++k4) {
        float4 w0 = Wl[k4 * 4 + 0][q];
        float4 w1 = Wl[k4 * 4 + 1][q];
        float4 w2 = Wl[k4 * 4 + 2][q];
        float4 w3 = Wl[k4 * 4 + 3][q];
        float4 x0 = xr[rbase + 0][k4];
        float4 x1 = xr[rbase + 1][k4];
        float4 x2 = xr[rbase + 2][k4];
        float4 x3 = xr[rbase + 3][k4];
        FMA4(acc0, x0.x, w0) FMA4(acc0, x0.y, w1) FMA4(acc0, x0.z, w2) FMA4(acc0, x0.w, w3)
        FMA4(acc1, x1.x, w0) FMA4(acc1, x1.y, w1) FMA4(acc1, x1.z, w2) FMA4(acc1, x1.w, w3)
        FMA4(acc2, x2.x, w0) FMA4(acc2, x2.y, w1) FMA4(acc2, x2.z, w2) FMA4(acc2, x2.w, w3)
        FMA4(acc3, x3.x, w0) FMA4(acc3, x3.y, w1) FMA4(acc3, x3.z, w2) FMA4(acc3, x3.w, w3)
    }

    const float4 ai = ((const float4*)att)[q];
    const float4 aj = ((const float4*)att)[16 + q];
    float4 accs[4] = {acc0, acc1, acc2, acc3};
#pragma unroll
    for (int rr = 0; rr < 4; ++rr) {
        int row = r0 + rbase + rr;
        if (row >= NN) continue;
        float4 a = accs[rr];
        ushort4 hv;
        hv.x = f2bf(a.x); hv.y = f2bf(a.y); hv.z = f2bf(a.z); hv.w = f2bf(a.w);
        hb[(size_t)row * 16 + q] = hv;
        float ps = a.x * ai.x + a.y * ai.y + a.z * ai.z + a.w * ai.w;
        float pt = a.x * aj.x + a.y * aj.y + a.z * aj.z + a.w * aj.w;
#pragma unroll
        for (int off = 1; off < 16; off <<= 1) {
            ps += __shfl_xor(ps, off);
            pt += __shfl_xor(pt, off);
        }
        if (q == 0) { s[row] = ps; t[row] = pt; }
    }
}

// ---------------- gather-softmax-aggregate over the NEEDED list only ----------------
// 4 nodes/wave, 16 lanes x 4 dims. Full 16-edge load batch (16 outstanding
// gathers/lane) + 4 independent accumulator chains. Invalid subs (past llen)
// use node 0 addresses with ev=0 and skip all writes.
__global__ __launch_bounds__(256) void k_gat(const ushort4* __restrict__ hb,
                                             const int* __restrict__ cnt,
                                             const int* __restrict__ esrc,
                                             const float* __restrict__ s,
                                             const float* __restrict__ t,
                                             const float* __restrict__ bias,
                                             const int* __restrict__ listlen,
                                             const int* __restrict__ list,
                                             float4* __restrict__ g4) {
    const int llen = *listlen;
    if (blockIdx.x * 16 >= llen) return;
    const int tid  = threadIdx.x;
    const int lane = tid & 63;
    const int w    = tid >> 6;
    const int q    = lane & 15;
    const int sub  = lane >> 4;
    const int gn   = blockIdx.x * 16 + w * 4 + sub;
    const int j    = (gn < llen) ? list[gn] : -1;
    const int jj   = (j < 0) ? 0 : j;
    const int lsrc = sub * 16;

    const float sj = s[jj];
    int deg = (j < 0) ? 0 : cnt[jj];
    if (deg > CAP) deg = CAP;
    const int base = jj * CAP;

    // parallel edge phase: lane q handles edges q, q+16, q+32, q+48 of its node
    int   sc[4];
    float ev[4];
#pragma unroll
    for (int u = 0; u < 4; ++u) {
        int e = q + u * 16;
        int srcn = 0; float evv = 0.f;
        if (e < deg) {
            srcn = __builtin_nontemporal_load(&esrc[base + e]);
            evv  = expf(leaky(sj + t[srcn]));
        }
        sc[u] = srcn; ev[u] = evv;
    }
    float den = ev[0] + ev[1] + ev[2] + ev[3];
#pragma unroll
    for (int off = 1; off < 16; off <<= 1) den += __shfl_xor(den, off);

    // self loop
    float evs = expf(leaky(sj + t[jj]));
    den += evs;
    float4 hj = ldh(hb, (size_t)jj * 16 + q);
    float4 a0, a1, a2, a3;
    a0.x = evs * hj.x; a0.y = evs * hj.y; a0.z = evs * hj.z; a0.w = evs * hj.w;
    a1 = make_float4(0.f, 0.f, 0.f, 0.f);
    a2 = a1; a3 = a1;

#pragma unroll
    for (int u = 0; u < 4; ++u) {
        if (!__any(deg > u * 16)) break;
        ushort4 vb[16];
#pragma unroll
        for (int kk = 0; kk < 16; ++kk) {
            int sK = __shfl(sc[u], lsrc + kk);
            vb[kk] = hb[(size_t)sK * 16 + q];
        }
#define STEP(kk, A) { float eK = __shfl(ev[u], lsrc + kk); \
                      float4 vv = cvt4(vb[kk]); FMA4(A, eK, vv) }
        STEP(0,  a0) STEP(1,  a1) STEP(2,  a2) STEP(3,  a3)
        STEP(4,  a0) STEP(5,  a1) STEP(6,  a2) STEP(7,  a3)
        STEP(8,  a0) STEP(9,  a1) STEP(10, a2) STEP(11, a3)
        STEP(12, a0) STEP(13, a1) STEP(14, a2) STEP(15, a3)
#undef STEP
    }
    float4 acc;
    acc.x = (a0.x + a1.x) + (a2.x + a3.x);
    acc.y = (a0.y + a1.y) + (a2.y + a3.y);
    acc.z = (a0.z + a1.z) + (a2.z + a3.z);
    acc.w = (a0.w + a1.w) + (a2.w + a3.w);

    float4 bv = ((const float4*)bias)[q];
    float inv = 1.0f / (den + 1e-16f);
    float4 v;
    v.x = acc.x * inv + bv.x; v.y = acc.y * inv + bv.y;
    v.z = acc.z * inv + bv.z; v.w = acc.w * inv + bv.w;
    float sq = v.x * v.x + v.y * v.y + v.z * v.z + v.w * v.w;
#pragma unroll
    for (int off = 1; off < 16; off <<= 1) sq += __shfl_xor(sq, off);
    float nm = fmaxf(sqrtf(sq), 1e-12f);
    if (j >= 0) {
        float4 o;
        o.x = v.x / nm; o.y = v.y / nm; o.z = v.z / nm; o.w = v.w / nm;
        g4[(size_t)j * 16 + q] = o;
    }
}

// ---------------- scores + reg loss ----------------
__global__ __launch_bounds__(256) void k5_score(const float4* __restrict__ X4,
                                                const float4* __restrict__ g4,
                                                const int* __restrict__ user,
                                                const int* __restrict__ pos,
                                                const int* __restrict__ neg,
                                                const int* __restrict__ posr,
                                                const int* __restrict__ negr,
                                                float* __restrict__ out) {
    const int tid  = threadIdx.x;
    const int lane = tid & 63;
    const int q    = lane & 15;
    const int sub  = lane >> 4;
    const int b    = blockIdx.x * 16 + (tid >> 6) * 4 + sub;

    int u = user[b], p = pos[b], n = neg[b], pr = posr[b], nr = negr[b];
    float4 xu = X4[(size_t)u * 16 + q],  gu = g4[(size_t)u * 16 + q];
    float4 xp = X4[(size_t)p * 16 + q],  gp = g4[(size_t)p * 16 + q];
    float4 xn = X4[(size_t)n * 16 + q],  gn = g4[(size_t)n * 16 + q];
    float4 xq = X4[(size_t)pr * 16 + q], gq = g4[(size_t)pr * 16 + q];
    float4 xm = X4[(size_t)nr * 16 + q], gm = g4[(size_t)nr * 16 + q];

#define DOT(a, c) (a.x * c.x + a.y * c.y + a.z * c.z + a.w * c.w)
    float dp = DOT(xu, xp) + DOT(gu, gp);
    float dn = DOT(xu, xn) + DOT(gu, gn);
    float dq = DOT(xu, xq) + DOT(gu, gq);
    float dm = DOT(xu, xm) + DOT(gu, gm);
    float rg = 0.5f    * (DOT(xu, xu) + DOT(gu, gu) + DOT(xp, xp) + DOT(gp, gp)
                        + DOT(xn, xn) + DOT(gn, gn))
             + 0.0005f * (DOT(xq, xq) + DOT(gq, gq) + DOT(xm, xm) + DOT(gm, gm));
#undef DOT
#pragma unroll
    for (int off = 1; off < 16; off <<= 1) {
        dp += __shfl_xor(dp, off);
        dn += __shfl_xor(dn, off);
        dq += __shfl_xor(dq, off);
        dm += __shfl_xor(dm, off);
    }
    if (q == 0) {
        out[b]      = dp + 0.1f * dq;
        out[BB + b] = dn + 0.1f * dm;
    }
#pragma unroll
    for (int off = 16; off < 64; off <<= 1) rg += __shfl_xor(rg, off);
#pragma unroll
    for (int off = 1; off < 16; off <<= 1) rg += __shfl_xor(rg, off);
    if (lane == 0) unsafeAtomicAdd(&out[2 * BB], rg);
}

extern "C" void kernel_launch(void* const* d_in, const int* in_sizes, int n_in,
                              void* d_out, int out_size, void* d_ws, size_t ws_size,
                              hipStream_t stream) {
    const float* X    = (const float*)d_in[0];
    const float* W    = (const float*)d_in[1];
    const float* att  = (const float*)d_in[2];
    const float* bias = (const float*)d_in[3];
    const int* edges  = (const int*)d_in[4];
    const int* user   = (const int*)d_in[5];
    const int* pos    = (const int*)d_in[6];
    const int* neg    = (const int*)d_in[7];
    const int* posr   = (const int*)d_in[8];
    const int* negr   = (const int*)d_in[9];
    float* out = (float*)d_out;

    // layout: hb | g4 | s | t | cnt | bitmap | listlen | list | esrc  (no memsets)
    ushort4*  hb      = (ushort4*)d_ws;                      // NN*16 ushort4 (bf16 h)
    float4*   g4      = (float4*)(hb + (size_t)NN * 16);     // NN*16 float4
    float*    s       = (float*)(g4 + (size_t)NN * 16);      // NN
    float*    t       = s + NN;                              // NN
    int*      cnt     = (int*)(t + NN);                      // NN (zeroed lazily in k_mark)
    unsigned* bitmap  = (unsigned*)(cnt + NN);               // BMW
    int*      listlen = (int*)(bitmap + BMW);                // 16 (padded)
    int*      list    = listlen + 16;                        // NLIST
    int*      esrc    = list + NLIST;                        // NN*CAP

    k_zero<<<(BMW + 255) / 256, 256, 0, stream>>>(bitmap, listlen, out);
    k_mark<<<80, 256, 0, stream>>>(user, pos, neg, posr, negr, bitmap, listlen, list, cnt);
    k_bucket<<<2048, 256, 0, stream>>>(edges, bitmap, cnt, esrc);
    k_mm<<<NMMB, 256, 0, stream>>>((const float4*)X, (const float4*)W, att, hb, s, t);
    k_gat<<<NGB, 256, 0, stream>>>(hb, cnt, esrc, s, t, bias, listlen, list, g4);
    k5_score<<<256, 256, 0, stream>>>((const float4*)X, g4, user, pos, neg, posr, negr, out);
}